// Round 15
// baseline (80.572 us; speedup 1.0000x reference)
//
#include <hip/hip_runtime.h>
#include <hip/hip_bf16.h>

#define B_ 4
#define C_ 256
#define N_ 4096
#define K_ 16
#define QB 64
#define FSCALE 1.2011224087864498f   // sqrt(log2(e)) -> QK^T comes out in log2 domain
#define EXPA 8388608.0f              // 2^23
#define EXPB 1065101558.0f           // (127 - 0.030)*2^23  (Schraudolph, balanced +/-3% rel err)

typedef float f32x4 __attribute__((ext_vector_type(4)));
typedef float f32x16 __attribute__((ext_vector_type(16)));
typedef short s16x8 __attribute__((ext_vector_type(8)));
typedef int   i32x4 __attribute__((ext_vector_type(4)));
typedef int   i32x2 __attribute__((ext_vector_type(2)));

__device__ __forceinline__ short f2bf(float f) {
  union { float f; unsigned u; } v; v.f = f;
  unsigned r = v.u + 0x7fffu + ((v.u >> 16) & 1u);
  return (short)(r >> 16);
}
__device__ __forceinline__ int packbf(float a, float b) {
  __hip_bfloat162 h = __float22bfloat162_rn(make_float2(a, b));
  int r; __builtin_memcpy(&r, &h, 4); return r;
}

// ---------------- pass 1 (fused): prep (blocks 0..255) + packv (blocks 256..767) ----------------
__global__ __launch_bounds__(256) void pre(const float* __restrict__ x,
                                           const float* __restrict__ w1,
                                           const float* __restrict__ b1,
                                           short* __restrict__ fT,
                                           short* __restrict__ vtP) {
  __shared__ __align__(16) char sm[20480];
  const int tid = threadIdx.x;
  if (blockIdx.x < 256) {
    float* w1t = (float*)sm;                    // [c][k] 16KB
    __shared__ float pr[4][64][17];
    for (int i = tid; i < C_ * K_; i += 256) {
      int k = i >> 8, c = i & 255;
      w1t[c * K_ + k] = w1[i];
    }
    __syncthreads();
    const int blk = blockIdx.x;
    const int b = blk >> 6;
    const int n0 = (blk & 63) * 64;
    const int nl = tid & 63;
    const int cch = tid >> 6;
    const int n = n0 + nl;
    const float* xp = x + (size_t)b * C_ * N_ + n;
    float acc[K_];
#pragma unroll
    for (int k = 0; k < K_; k++) acc[k] = 0.f;
    for (int cc = 0; cc < 64; cc++) {
      int c = cch * 64 + cc;
      float v = xp[(size_t)c * N_];
      const f32x4* wp = (const f32x4*)(&w1t[c * K_]);
#pragma unroll
      for (int qq = 0; qq < 4; qq++) {
        f32x4 wv = wp[qq];
#pragma unroll
        for (int j = 0; j < 4; j++) acc[qq * 4 + j] += wv[j] * v;
      }
    }
#pragma unroll
    for (int k = 0; k < K_; k++) pr[cch][nl][k] = acc[k];
    __syncthreads();
#pragma unroll
    for (int jj = 0; jj < 4; jj++) {
      int o = tid + jj * 256;
      int on = o >> 4, ok = o & 15;
      float s = pr[0][on][ok] + pr[1][on][ok] + pr[2][on][ok] + pr[3][on][ok] + b1[ok];
      fT[((size_t)b * N_ + n0 + on) * K_ + ok] = f2bf(s * FSCALE);
    }
  } else {
    short* t = (short*)sm;         // [64][136] shorts, XOR-swizzled 8-short blocks
    const int bid = blockIdx.x - 256;   // 512 = 4b x 4cb x 32nb
    const int b = bid >> 7, cb = (bid >> 5) & 3, nb = bid & 31;
    const int n0 = nb * 128, c0 = cb * 64;
    const int r = tid >> 2, cg = tid & 3;
    const float* xp = x + ((size_t)(b * 256 + c0 + r)) * N_ + n0 + cg * 32;
#pragma unroll
    for (int k = 0; k < 8; k++) {
      f32x4 v = *(const f32x4*)(xp + k * 4);
      i32x2 p = {packbf(v[0], v[1]), packbf(v[2], v[3])};
      int col = (cg * 32 + k * 4) ^ ((r & 7) * 8);
      *(i32x2*)(&t[r * 136 + col]) = p;
    }
    __syncthreads();
#pragma unroll
    for (int u = 0; u < 4; u++) {
      int chunk = tid + 256 * u;          // 1024 = 16 gl x 64 c
      int gl = chunk >> 6, c = chunk & 63;
      int m16 = gl >> 1, hi = gl & 1;
      int swz = (c & 7) * 8;
      i32x2 a = *(const i32x2*)(&t[c * 136 + ((m16 * 16 + hi * 4) ^ swz)]);
      i32x2 bq = *(const i32x2*)(&t[c * 136 + ((m16 * 16 + 8 + hi * 4) ^ swz)]);
      i32x4 vv = {a[0], a[1], bq[0], bq[1]};
      size_t g = (size_t)b * 512 + (size_t)(nb * 8 + m16) * 2 + hi;
      *(i32x4*)(vtP + (g * 256 + c0 + c) * 8) = vv;
    }
  }
}

// ---------------- pass 2: R14 frozen shape + 1-iter register rotation + cs-stagger ----------
// Shape FROZEN (R10/R11/R13 lesson): 16 waves = h(2) x nt(2) x cs(4), 32 iters, QB 64, grid 256,
// NO unroll pragma. New: (a) operands prefetched one iteration ahead in registers with R9's
// placement (next-K after QK, next-V after PV) but WITHOUT unroll-1, so the compiler can still
// unroll/pipeline on top; (b) cs-groups start at m-offset cs*8 (mod-32 wrap — legal because the
// no-max softmax is a pure commutative sum), decorrelating the 4 groups' L2 bursts per CU.
__global__ __launch_bounds__(1024) void flash11(const float* __restrict__ x,
                                                const short* __restrict__ vtP,
                                                const short* __restrict__ fT,
                                                float* __restrict__ out) {
  __shared__ __align__(16) char lds[65536];   // epilogue h-merge only
  const int tid = threadIdx.x;
  const int l = tid & 63;
  const int w = tid >> 6;
  const int h = w >> 3;
  const int wu = w & 7;
  const int nt = wu >> 2;
  const int cs = wu & 3;
  const int hi = l >> 5;
  const int q = l & 31;
  const int id = blockIdx.x;
  const int b = id & 3;            // XCD (id&7) -> fixed batch (vtP[b] = 2MB < 4MB L2)
  const int n0 = (id >> 2) * QB;

  const short* fTb = fT + (size_t)b * N_ * K_;
  const int mh0 = h * 2048;

  const s16x8 qf = *(const s16x8*)(fTb + (size_t)(n0 + nt * 32 + q) * K_ + hi * 8);
  const short* pkb = fTb + (size_t)(mh0 + q) * K_ + hi * 8;
  const short* pvb = vtP + (((size_t)b * 512 + (mh0 >> 4) * 2 + hi) * 256 + cs * 64 + q) * 8;

  f32x16 zero16 = {};
  f32x16 acc0 = zero16, acc1 = zero16;
  float lrun = 0.f;

  const int it0 = cs * 8;  // stagger: cs-groups walk m starting at different offsets

  // prologue: operands for the first m-tile
  s16x8 kf0, kf1, vA0, vB0, vA1, vB1, vA2, vB2, vA3, vB3;
  {
    const short* pk = pkb + it0 * 1024;
    const short* pv = pvb + it0 * 16384;
    kf0 = *(const s16x8*)(pk);
    kf1 = *(const s16x8*)(pk + 32 * K_);
    vA0 = *(const s16x8*)(pv);
    vB0 = *(const s16x8*)(pv + 256);
    vA1 = *(const s16x8*)(pv + 4096);
    vB1 = *(const s16x8*)(pv + 4096 + 256);
    vA2 = *(const s16x8*)(pv + 8192);
    vB2 = *(const s16x8*)(pv + 8192 + 256);
    vA3 = *(const s16x8*)(pv + 12288);
    vB3 = *(const s16x8*)(pv + 12288 + 256);
  }

  for (int it = 0; it < 32; ++it) {
    const int nmi = (it0 + it + 1) & 31;   // wrap: last iter prefetch re-reads tile it0 (discarded)
    const short* pkn = pkb + nmi * 1024;
    const short* pvn = pvb + nmi * 16384;

    __builtin_amdgcn_s_setprio(1);

    // QK^T: S'[m][n] (log2 domain), two 32x32 tiles (consumes kf, prefetched last iter)
    f32x16 st0 = __builtin_amdgcn_mfma_f32_32x32x16_bf16(kf0, qf, zero16, 0, 0, 0);
    f32x16 st1 = __builtin_amdgcn_mfma_f32_32x32x16_bf16(kf1, qf, zero16, 0, 0, 0);

    // prefetch next K (consumed next iter's QK — ~full iteration of latency cover)
    s16x8 nk0 = *(const s16x8*)(pkn);
    s16x8 nk1 = *(const s16x8*)(pkn + 32 * K_);

    // P = exp2(S') via Schraudolph int-fma; bf16 pair-pack = single v_perm_b32
    int sd0[8], sd1[8];
    float ps0 = 0.f, ps1 = 0.f, ps2 = 0.f, ps3 = 0.f;
#pragma unroll
    for (int s2 = 0; s2 < 8; s2++) {
      int ia = (int)(st0[2 * s2] * EXPA + EXPB);
      int ib = (int)(st0[2 * s2 + 1] * EXPA + EXPB);
      ps0 += __int_as_float(ia);
      ps1 += __int_as_float(ib);
      sd0[s2] = (int)__builtin_amdgcn_perm((unsigned)ib, (unsigned)ia, 0x07060302u);
    }
#pragma unroll
    for (int s2 = 0; s2 < 8; s2++) {
      int ia = (int)(st1[2 * s2] * EXPA + EXPB);
      int ib = (int)(st1[2 * s2 + 1] * EXPA + EXPB);
      ps2 += __int_as_float(ia);
      ps3 += __int_as_float(ib);
      sd1[s2] = (int)__builtin_amdgcn_perm((unsigned)ib, (unsigned)ia, 0x07060302u);
    }
    lrun += (ps0 + ps1) + (ps2 + ps3);

    // PV: acc[ct] (O^T[c][n]) += V~[c][k] * P~[k][n] (consumes vf, prefetched last iter)
    {
      i32x4 p0 = {sd0[0], sd0[1], sd0[2], sd0[3]};
      s16x8 pf = __builtin_bit_cast(s16x8, p0);
      acc0 = __builtin_amdgcn_mfma_f32_32x32x16_bf16(vA0, pf, acc0, 0, 0, 0);
      acc1 = __builtin_amdgcn_mfma_f32_32x32x16_bf16(vB0, pf, acc1, 0, 0, 0);
    }
    {
      i32x4 p1 = {sd0[4], sd0[5], sd0[6], sd0[7]};
      s16x8 pf = __builtin_bit_cast(s16x8, p1);
      acc0 = __builtin_amdgcn_mfma_f32_32x32x16_bf16(vA1, pf, acc0, 0, 0, 0);
      acc1 = __builtin_amdgcn_mfma_f32_32x32x16_bf16(vB1, pf, acc1, 0, 0, 0);
    }
    {
      i32x4 p2 = {sd1[0], sd1[1], sd1[2], sd1[3]};
      s16x8 pf = __builtin_bit_cast(s16x8, p2);
      acc0 = __builtin_amdgcn_mfma_f32_32x32x16_bf16(vA2, pf, acc0, 0, 0, 0);
      acc1 = __builtin_amdgcn_mfma_f32_32x32x16_bf16(vB2, pf, acc1, 0, 0, 0);
    }
    {
      i32x4 p3 = {sd1[4], sd1[5], sd1[6], sd1[7]};
      s16x8 pf = __builtin_bit_cast(s16x8, p3);
      acc0 = __builtin_amdgcn_mfma_f32_32x32x16_bf16(vA3, pf, acc0, 0, 0, 0);
      acc1 = __builtin_amdgcn_mfma_f32_32x32x16_bf16(vB3, pf, acc1, 0, 0, 0);
    }

    __builtin_amdgcn_s_setprio(0);

    // prefetch next V (consumed after next iter's QK+exp — ample cover)
    vA0 = *(const s16x8*)(pvn);
    vB0 = *(const s16x8*)(pvn + 256);
    vA1 = *(const s16x8*)(pvn + 4096);
    vB1 = *(const s16x8*)(pvn + 4096 + 256);
    vA2 = *(const s16x8*)(pvn + 8192);
    vB2 = *(const s16x8*)(pvn + 8192 + 256);
    vA3 = *(const s16x8*)(pvn + 12288);
    vB3 = *(const s16x8*)(pvn + 12288 + 256);
    kf0 = nk0; kf1 = nk1;
  }

  // hi-partner combine of l (purely additive)
  lrun += __shfl_xor(lrun, 32);

  // ---------------- merge the two m-halves + epilogue ----------------
  float* mlb = (float*)lds;             // [16 waves][64 lanes]
  mlb[w * 64 + l] = lrun;
  __syncthreads();
  const float L = lrun + mlb[(w ^ 8) * 64 + l];
  __syncthreads();
  char* xch = lds;                      // [8 wu][64 l][128B], swizzled
  const int xbase = (wu * 64 + l) * 128;
  if (h == 1) {
#pragma unroll
    for (int i = 0; i < 8; i++) {
      f32x4 v;
#pragma unroll
      for (int r = 0; r < 4; r++) v[r] = (i >> 2) ? acc1[(i & 3) * 4 + r] : acc0[(i & 3) * 4 + r];
      *(f32x4*)(xch + xbase + ((i * 16) ^ ((l & 7) << 4))) = v;
    }
  }
  __syncthreads();
  if (h == 0) {
    const float invL = 0.1f / L;
    const int n = n0 + nt * 32 + q;
#pragma unroll
    for (int i = 0; i < 8; i++) {
      f32x4 po = *(const f32x4*)(xch + xbase + ((i * 16) ^ ((l & 7) << 4)));
      const int p_ = i & 3;
      const int cbase = cs * 64 + (i >> 2) * 32 + p_ * 8 + hi * 4;
#pragma unroll
      for (int r = 0; r < 4; r++) {
        const float own = (i >> 2) ? acc1[p_ * 4 + r] : acc0[p_ * 4 + r];
        const size_t idx = ((size_t)b * C_ + (cbase + r)) * N_ + n;
        out[idx] = x[idx] + (own + po[r]) * invL;
      }
    }
  }
}

extern "C" void kernel_launch(void* const* d_in, const int* in_sizes, int n_in,
                              void* d_out, int out_size, void* d_ws, size_t ws_size,
                              hipStream_t stream) {
  const float* x  = (const float*)d_in[0];
  const float* w1 = (const float*)d_in[1];
  const float* b1 = (const float*)d_in[2];
  float* out = (float*)d_out;
  short* fT  = (short*)d_ws;                         // [B][N][16] bf16, 512KB
  short* vtP = (short*)((char*)d_ws + 512 * 1024);   // [B][512][256][8] bf16, 8MB
  pre<<<dim3(768), dim3(256), 0, stream>>>(x, w1, b1, fT, vtP);
  flash11<<<dim3(256), dim3(1024), 0, stream>>>(x, vtP, fT, out);
}

// Round 16
// 71.256 us; speedup vs baseline: 1.1307x; 1.1307x over previous
//
#include <hip/hip_runtime.h>
#include <hip/hip_bf16.h>

#define B_ 4
#define C_ 256
#define N_ 4096
#define K_ 16
#define QB 64
#define FSCALE 1.2011224087864498f   // sqrt(log2(e)) -> QK^T comes out in log2 domain
#define EXPA 8388608.0f              // 2^23
#define EXPB 1065101558.0f           // (127 - 0.030)*2^23  (Schraudolph, balanced +/-3% rel err)

typedef float f32x4 __attribute__((ext_vector_type(4)));
typedef float f32x16 __attribute__((ext_vector_type(16)));
typedef short s16x8 __attribute__((ext_vector_type(8)));
typedef int   i32x4 __attribute__((ext_vector_type(4)));
typedef int   i32x2 __attribute__((ext_vector_type(2)));

__device__ __forceinline__ short f2bf(float f) {
  union { float f; unsigned u; } v; v.f = f;
  unsigned r = v.u + 0x7fffu + ((v.u >> 16) & 1u);
  return (short)(r >> 16);
}
__device__ __forceinline__ int packbf(float a, float b) {
  __hip_bfloat162 h = __float22bfloat162_rn(make_float2(a, b));
  int r; __builtin_memcpy(&r, &h, 4); return r;
}

// ---------------- pass 1 (fused): prep (blocks 0..255) + packv (blocks 256..767) ----------------
__global__ __launch_bounds__(256) void pre(const float* __restrict__ x,
                                           const float* __restrict__ w1,
                                           const float* __restrict__ b1,
                                           short* __restrict__ fT,
                                           short* __restrict__ vtP) {
  __shared__ __align__(16) char sm[20480];
  const int tid = threadIdx.x;
  if (blockIdx.x < 256) {
    float* w1t = (float*)sm;                    // [c][k] 16KB
    __shared__ float pr[4][64][17];
    for (int i = tid; i < C_ * K_; i += 256) {
      int k = i >> 8, c = i & 255;
      w1t[c * K_ + k] = w1[i];
    }
    __syncthreads();
    const int blk = blockIdx.x;
    const int b = blk >> 6;
    const int n0 = (blk & 63) * 64;
    const int nl = tid & 63;
    const int cch = tid >> 6;
    const int n = n0 + nl;
    const float* xp = x + (size_t)b * C_ * N_ + n;
    float acc[K_];
#pragma unroll
    for (int k = 0; k < K_; k++) acc[k] = 0.f;
    for (int cc = 0; cc < 64; cc++) {
      int c = cch * 64 + cc;
      float v = xp[(size_t)c * N_];
      const f32x4* wp = (const f32x4*)(&w1t[c * K_]);
#pragma unroll
      for (int qq = 0; qq < 4; qq++) {
        f32x4 wv = wp[qq];
#pragma unroll
        for (int j = 0; j < 4; j++) acc[qq * 4 + j] += wv[j] * v;
      }
    }
#pragma unroll
    for (int k = 0; k < K_; k++) pr[cch][nl][k] = acc[k];
    __syncthreads();
#pragma unroll
    for (int jj = 0; jj < 4; jj++) {
      int o = tid + jj * 256;
      int on = o >> 4, ok = o & 15;
      float s = pr[0][on][ok] + pr[1][on][ok] + pr[2][on][ok] + pr[3][on][ok] + b1[ok];
      fT[((size_t)b * N_ + n0 + on) * K_ + ok] = f2bf(s * FSCALE);
    }
  } else {
    short* t = (short*)sm;         // [64][136] shorts, XOR-swizzled 8-short blocks
    const int bid = blockIdx.x - 256;   // 512 = 4b x 4cb x 32nb
    const int b = bid >> 7, cb = (bid >> 5) & 3, nb = bid & 31;
    const int n0 = nb * 128, c0 = cb * 64;
    const int r = tid >> 2, cg = tid & 3;
    const float* xp = x + ((size_t)(b * 256 + c0 + r)) * N_ + n0 + cg * 32;
#pragma unroll
    for (int k = 0; k < 8; k++) {
      f32x4 v = *(const f32x4*)(xp + k * 4);
      i32x2 p = {packbf(v[0], v[1]), packbf(v[2], v[3])};
      int col = (cg * 32 + k * 4) ^ ((r & 7) * 8);
      *(i32x2*)(&t[r * 136 + col]) = p;
    }
    __syncthreads();
#pragma unroll
    for (int u = 0; u < 4; u++) {
      int chunk = tid + 256 * u;          // 1024 = 16 gl x 64 c
      int gl = chunk >> 6, c = chunk & 63;
      int m16 = gl >> 1, hi = gl & 1;
      int swz = (c & 7) * 8;
      i32x2 a = *(const i32x2*)(&t[c * 136 + ((m16 * 16 + hi * 4) ^ swz)]);
      i32x2 bq = *(const i32x2*)(&t[c * 136 + ((m16 * 16 + 8 + hi * 4) ^ swz)]);
      i32x4 vv = {a[0], a[1], bq[0], bq[1]};
      size_t g = (size_t)b * 512 + (size_t)(nb * 8 + m16) * 2 + hi;
      *(i32x4*)(vtP + (g * 256 + c0 + c) * 8) = vv;
    }
  }
}

// ---------------- pass 2: shared-P flash — exp/QK dup eliminated via LDS P-exchange ----------
// Wave map frozen: 16 waves = h(2) x nt(2) x cs(4); lane (q,hi); grid 256; NO unroll pragmas.
// 8 super-iters of 256 m (per h-half): wave QKs+exps its OWN 64-m tile (mt=cs) -> packs P
// (Schraudolph, bit-identical to R12/R14) -> 4 x b128 LDS write -> barrier -> PV over all
// 4 tiles (32 MFMA, pf via conflict-free b128 LDS reads) -> barrier. C/D-reg r of st equals
// B-fragment element j of the vtP-permuted layout (r=j), so the LDS write is a direct sd dump.
// P buffer [h][nt]: slot ((mt*4+m16)*2+hi)*32+q)*16B = 16KB each, 64KB total.
__global__ __launch_bounds__(1024) void flash12(const float* __restrict__ x,
                                                const short* __restrict__ vtP,
                                                const short* __restrict__ fT,
                                                float* __restrict__ out) {
  __shared__ __align__(16) char lds[65536];
  const int tid = threadIdx.x;
  const int l = tid & 63;
  const int w = tid >> 6;
  const int h = w >> 3;
  const int wu = w & 7;
  const int nt = wu >> 2;
  const int cs = wu & 3;
  const int hi = l >> 5;
  const int q = l & 31;
  const int id = blockIdx.x;
  const int b = id & 3;            // XCD (id&7) -> fixed batch (vtP[b] = 2MB < 4MB L2)
  const int n0 = (id >> 2) * QB;

  const short* fTb = fT + (size_t)b * N_ * K_;
  const int mh0 = h * 2048;

  const s16x8 qf = *(const s16x8*)(fTb + (size_t)(n0 + nt * 32 + q) * K_ + hi * 8);
  // own QK m-tile: mh0 + si*256 + cs*64
  const short* pkb = fTb + (size_t)(mh0 + cs * 64 + q) * K_ + hi * 8;
  const short* pvb = vtP + (((size_t)b * 512 + (mh0 >> 4) * 2 + hi) * 256 + cs * 64 + q) * 8;

  const int pO = (h * 2 + nt) * 16384 + q * 16 + hi * 512;  // P-buffer lane base

  f32x16 zero16 = {};
  f32x16 acc0 = zero16, acc1 = zero16;
  float lrun = 0.f;

  for (int si = 0; si < 8; ++si) {
    // ---- produce own P tile (mt = cs) ----
    const short* pk = pkb + si * 256 * K_;
    s16x8 kf0 = *(const s16x8*)(pk);
    s16x8 kf1 = *(const s16x8*)(pk + 32 * K_);

    __builtin_amdgcn_s_setprio(1);
    f32x16 st0 = __builtin_amdgcn_mfma_f32_32x32x16_bf16(kf0, qf, zero16, 0, 0, 0);
    f32x16 st1 = __builtin_amdgcn_mfma_f32_32x32x16_bf16(kf1, qf, zero16, 0, 0, 0);

    int sd0[8], sd1[8];
    float ps0 = 0.f, ps1 = 0.f, ps2 = 0.f, ps3 = 0.f;
#pragma unroll
    for (int s2 = 0; s2 < 8; s2++) {
      int ia = (int)(st0[2 * s2] * EXPA + EXPB);
      int ib = (int)(st0[2 * s2 + 1] * EXPA + EXPB);
      ps0 += __int_as_float(ia);
      ps1 += __int_as_float(ib);
      sd0[s2] = (int)__builtin_amdgcn_perm((unsigned)ib, (unsigned)ia, 0x07060302u);
    }
#pragma unroll
    for (int s2 = 0; s2 < 8; s2++) {
      int ia = (int)(st1[2 * s2] * EXPA + EXPB);
      int ib = (int)(st1[2 * s2 + 1] * EXPA + EXPB);
      ps2 += __int_as_float(ia);
      ps3 += __int_as_float(ib);
      sd1[s2] = (int)__builtin_amdgcn_perm((unsigned)ib, (unsigned)ia, 0x07060302u);
    }
    lrun += (ps0 + ps1) + (ps2 + ps3);
    __builtin_amdgcn_s_setprio(0);

    {  // LDS write: fragments m16 = 0..3 at slot base + cs*4096 (mt = cs)
      char* pwr = lds + pO + cs * 4096;
      *(i32x4*)(pwr)        = (i32x4){sd0[0], sd0[1], sd0[2], sd0[3]};
      *(i32x4*)(pwr + 1024) = (i32x4){sd0[4], sd0[5], sd0[6], sd0[7]};
      *(i32x4*)(pwr + 2048) = (i32x4){sd1[0], sd1[1], sd1[2], sd1[3]};
      *(i32x4*)(pwr + 3072) = (i32x4){sd1[4], sd1[5], sd1[6], sd1[7]};
    }
    __syncthreads();

    // ---- PV over the 4 shared tiles ----
    __builtin_amdgcn_s_setprio(1);
#pragma unroll
    for (int mt = 0; mt < 4; ++mt) {
      const short* pv = pvb + (size_t)(si * 4 + mt) * 16384;
      s16x8 vA0 = *(const s16x8*)(pv);
      s16x8 vB0 = *(const s16x8*)(pv + 256);
      s16x8 vA1 = *(const s16x8*)(pv + 4096);
      s16x8 vB1 = *(const s16x8*)(pv + 4096 + 256);
      s16x8 vA2 = *(const s16x8*)(pv + 8192);
      s16x8 vB2 = *(const s16x8*)(pv + 8192 + 256);
      s16x8 vA3 = *(const s16x8*)(pv + 12288);
      s16x8 vB3 = *(const s16x8*)(pv + 12288 + 256);
      const char* prd = lds + pO + mt * 4096;
      s16x8 pf0 = __builtin_bit_cast(s16x8, *(const i32x4*)(prd));
      s16x8 pf1 = __builtin_bit_cast(s16x8, *(const i32x4*)(prd + 1024));
      s16x8 pf2 = __builtin_bit_cast(s16x8, *(const i32x4*)(prd + 2048));
      s16x8 pf3 = __builtin_bit_cast(s16x8, *(const i32x4*)(prd + 3072));
      acc0 = __builtin_amdgcn_mfma_f32_32x32x16_bf16(vA0, pf0, acc0, 0, 0, 0);
      acc1 = __builtin_amdgcn_mfma_f32_32x32x16_bf16(vB0, pf0, acc1, 0, 0, 0);
      acc0 = __builtin_amdgcn_mfma_f32_32x32x16_bf16(vA1, pf1, acc0, 0, 0, 0);
      acc1 = __builtin_amdgcn_mfma_f32_32x32x16_bf16(vB1, pf1, acc1, 0, 0, 0);
      acc0 = __builtin_amdgcn_mfma_f32_32x32x16_bf16(vA2, pf2, acc0, 0, 0, 0);
      acc1 = __builtin_amdgcn_mfma_f32_32x32x16_bf16(vB2, pf2, acc1, 0, 0, 0);
      acc0 = __builtin_amdgcn_mfma_f32_32x32x16_bf16(vA3, pf3, acc0, 0, 0, 0);
      acc1 = __builtin_amdgcn_mfma_f32_32x32x16_bf16(vB3, pf3, acc1, 0, 0, 0);
    }
    __builtin_amdgcn_s_setprio(0);
    __syncthreads();
  }

  // hi-partner combine of own-tile l sums
  lrun += __shfl_xor(lrun, 32);

  // ---------------- epilogue: L = sum of the 8 (h,cs) wave sums sharing nt ----------------
  float* mlb = (float*)lds;             // [16 waves][64 lanes]
  mlb[w * 64 + l] = lrun;
  __syncthreads();
  float L = 0.f;
#pragma unroll
  for (int hh = 0; hh < 2; ++hh)
#pragma unroll
    for (int cc = 0; cc < 4; ++cc)
      L += mlb[(hh * 8 + nt * 4 + cc) * 64 + l];
  __syncthreads();
  char* xch = lds;                      // [8 wu][64 l][128B], swizzled
  const int xbase = (wu * 64 + l) * 128;
  if (h == 1) {
#pragma unroll
    for (int i = 0; i < 8; i++) {
      f32x4 v;
#pragma unroll
      for (int r = 0; r < 4; r++) v[r] = (i >> 2) ? acc1[(i & 3) * 4 + r] : acc0[(i & 3) * 4 + r];
      *(f32x4*)(xch + xbase + ((i * 16) ^ ((l & 7) << 4))) = v;
    }
  }
  __syncthreads();
  if (h == 0) {
    const float invL = 0.1f / L;
    const int n = n0 + nt * 32 + q;
#pragma unroll
    for (int i = 0; i < 8; i++) {
      f32x4 po = *(const f32x4*)(xch + xbase + ((i * 16) ^ ((l & 7) << 4)));
      const int p_ = i & 3;
      const int cbase = cs * 64 + (i >> 2) * 32 + p_ * 8 + hi * 4;
#pragma unroll
      for (int r = 0; r < 4; r++) {
        const float own = (i >> 2) ? acc1[p_ * 4 + r] : acc0[p_ * 4 + r];
        const size_t idx = ((size_t)b * C_ + (cbase + r)) * N_ + n;
        out[idx] = x[idx] + (own + po[r]) * invL;
      }
    }
  }
}

extern "C" void kernel_launch(void* const* d_in, const int* in_sizes, int n_in,
                              void* d_out, int out_size, void* d_ws, size_t ws_size,
                              hipStream_t stream) {
  const float* x  = (const float*)d_in[0];
  const float* w1 = (const float*)d_in[1];
  const float* b1 = (const float*)d_in[2];
  float* out = (float*)d_out;
  short* fT  = (short*)d_ws;                         // [B][N][16] bf16, 512KB
  short* vtP = (short*)((char*)d_ws + 512 * 1024);   // [B][512][256][8] bf16, 8MB
  pre<<<dim3(768), dim3(256), 0, stream>>>(x, w1, b1, fT, vtP);
  flash12<<<dim3(256), dim3(1024), 0, stream>>>(x, vtP, fT, out);
}

// Round 17
// 65.646 us; speedup vs baseline: 1.2274x; 1.0855x over previous
//
#include <hip/hip_runtime.h>
#include <hip/hip_bf16.h>

#define B_ 4
#define C_ 256
#define N_ 4096
#define K_ 16
#define QB 64
#define FSCALE 1.2011224087864498f   // sqrt(log2(e)) -> QK^T comes out in log2 domain
#define EXPA 8388608.0f              // 2^23
#define EXPB 1065101558.0f           // (127 - 0.030)*2^23  (Schraudolph, balanced +/-3% rel err)

typedef float f32x4 __attribute__((ext_vector_type(4)));
typedef float f32x16 __attribute__((ext_vector_type(16)));
typedef short s16x8 __attribute__((ext_vector_type(8)));
typedef int   i32x4 __attribute__((ext_vector_type(4)));
typedef int   i32x2 __attribute__((ext_vector_type(2)));

__device__ __forceinline__ short f2bf(float f) {
  union { float f; unsigned u; } v; v.f = f;
  unsigned r = v.u + 0x7fffu + ((v.u >> 16) & 1u);
  return (short)(r >> 16);
}
__device__ __forceinline__ int packbf(float a, float b) {
  __hip_bfloat162 h = __float22bfloat162_rn(make_float2(a, b));
  int r; __builtin_memcpy(&r, &h, 4); return r;
}

// ---------------- pass 1 (fused): prep (blocks 0..255) + packv (blocks 256..767) ----------------
__global__ __launch_bounds__(256) void pre(const float* __restrict__ x,
                                           const float* __restrict__ w1,
                                           const float* __restrict__ b1,
                                           short* __restrict__ fT,
                                           short* __restrict__ vtP) {
  __shared__ __align__(16) char sm[20480];
  const int tid = threadIdx.x;
  if (blockIdx.x < 256) {
    float* w1t = (float*)sm;                    // [c][k] 16KB
    __shared__ float pr[4][64][17];
    for (int i = tid; i < C_ * K_; i += 256) {
      int k = i >> 8, c = i & 255;
      w1t[c * K_ + k] = w1[i];
    }
    __syncthreads();
    const int blk = blockIdx.x;
    const int b = blk >> 6;
    const int n0 = (blk & 63) * 64;
    const int nl = tid & 63;
    const int cch = tid >> 6;
    const int n = n0 + nl;
    const float* xp = x + (size_t)b * C_ * N_ + n;
    float acc[K_];
#pragma unroll
    for (int k = 0; k < K_; k++) acc[k] = 0.f;
    for (int cc = 0; cc < 64; cc++) {
      int c = cch * 64 + cc;
      float v = xp[(size_t)c * N_];
      const f32x4* wp = (const f32x4*)(&w1t[c * K_]);
#pragma unroll
      for (int qq = 0; qq < 4; qq++) {
        f32x4 wv = wp[qq];
#pragma unroll
        for (int j = 0; j < 4; j++) acc[qq * 4 + j] += wv[j] * v;
      }
    }
#pragma unroll
    for (int k = 0; k < K_; k++) pr[cch][nl][k] = acc[k];
    __syncthreads();
#pragma unroll
    for (int jj = 0; jj < 4; jj++) {
      int o = tid + jj * 256;
      int on = o >> 4, ok = o & 15;
      float s = pr[0][on][ok] + pr[1][on][ok] + pr[2][on][ok] + pr[3][on][ok] + b1[ok];
      fT[((size_t)b * N_ + n0 + on) * K_ + ok] = f2bf(s * FSCALE);
    }
  } else {
    short* t = (short*)sm;         // [64][136] shorts, XOR-swizzled 8-short blocks
    const int bid = blockIdx.x - 256;   // 512 = 4b x 4cb x 32nb
    const int b = bid >> 7, cb = (bid >> 5) & 3, nb = bid & 31;
    const int n0 = nb * 128, c0 = cb * 64;
    const int r = tid >> 2, cg = tid & 3;
    const float* xp = x + ((size_t)(b * 256 + c0 + r)) * N_ + n0 + cg * 32;
#pragma unroll
    for (int k = 0; k < 8; k++) {
      f32x4 v = *(const f32x4*)(xp + k * 4);
      i32x2 p = {packbf(v[0], v[1]), packbf(v[2], v[3])};
      int col = (cg * 32 + k * 4) ^ ((r & 7) * 8);
      *(i32x2*)(&t[r * 136 + col]) = p;
    }
    __syncthreads();
#pragma unroll
    for (int u = 0; u < 4; u++) {
      int chunk = tid + 256 * u;          // 1024 = 16 gl x 64 c
      int gl = chunk >> 6, c = chunk & 63;
      int m16 = gl >> 1, hi = gl & 1;
      int swz = (c & 7) * 8;
      i32x2 a = *(const i32x2*)(&t[c * 136 + ((m16 * 16 + hi * 4) ^ swz)]);
      i32x2 bq = *(const i32x2*)(&t[c * 136 + ((m16 * 16 + 8 + hi * 4) ^ swz)]);
      i32x4 vv = {a[0], a[1], bq[0], bq[1]};
      size_t g = (size_t)b * 512 + (size_t)(nb * 8 + m16) * 2 + hi;
      *(i32x4*)(vtP + (g * 256 + c0 + c) * 8) = vv;
    }
  }
}

// ---------------- pass 2: shared-P + shared-V flash (V read once, applied to both nt) --------
// 16 waves = h(2) x u(8). Production role: (mt_p = u>>1, nt_p = u&1) — one 64m x 32n P-tile per
// wave (exp dedup preserved). PV role: c-span u*32 (32 channels), BOTH nt tiles — V fragments
// loaded once, used twice -> per-block V traffic 4MB -> 2MB (the R16 limiter).
// P LDS: slot ((h*2+nt)*4 + mt)*4096 + m16*1024 + hi*512 + q*16 = 64KB. 2 barriers per si.
// Grid 256, no unroll pragmas, loads-at-top, Schraudolph exp2 (bit-identical P).
__global__ __launch_bounds__(1024) void flash13(const float* __restrict__ x,
                                                const short* __restrict__ vtP,
                                                const short* __restrict__ fT,
                                                float* __restrict__ out) {
  __shared__ __align__(16) char lds[65536];
  const int tid = threadIdx.x;
  const int l = tid & 63;
  const int w = tid >> 6;
  const int h = w >> 3;
  const int u = w & 7;
  const int mt_p = u >> 1;
  const int nt_p = u & 1;
  const int hi = l >> 5;
  const int q = l & 31;
  const int id = blockIdx.x;
  const int b = id & 3;            // XCD (id&7) -> fixed batch (vtP[b] = 2MB < 4MB L2)
  const int n0 = (id >> 2) * QB;

  const short* fTb = fT + (size_t)b * N_ * K_;
  const int mh0 = h * 2048;

  // Q fragment for production: n-col = n0 + nt_p*32 + q
  const s16x8 qf = *(const s16x8*)(fTb + (size_t)(n0 + nt_p * 32 + q) * K_ + hi * 8);
  // K rows for production m-tile: mh0 + si*256 + mt_p*64
  const short* pkb = fTb + (size_t)(mh0 + mt_p * 64 + q) * K_ + hi * 8;
  // V for PV: c-span u*32, this h-half
  const short* pvb = vtP + (((size_t)b * 512 + (mh0 >> 4) * 2 + hi) * 256 + u * 32 + q) * 8;

  char* pwr = lds + ((h * 2 + nt_p) * 4 + mt_p) * 4096 + hi * 512 + q * 16;
  const int prdO = hi * 512 + q * 16;

  f32x16 zero16 = {};
  f32x16 acc0 = zero16, acc1 = zero16;   // acc0 = nt0, acc1 = nt1 (same 32-c span)
  float lrun = 0.f;

  for (int si = 0; si < 8; ++si) {
    // ---- produce own P tile (mt_p, nt_p) ----
    const short* pk = pkb + si * 256 * K_;
    s16x8 kf0 = *(const s16x8*)(pk);
    s16x8 kf1 = *(const s16x8*)(pk + 32 * K_);

    __builtin_amdgcn_s_setprio(1);
    f32x16 st0 = __builtin_amdgcn_mfma_f32_32x32x16_bf16(kf0, qf, zero16, 0, 0, 0);
    f32x16 st1 = __builtin_amdgcn_mfma_f32_32x32x16_bf16(kf1, qf, zero16, 0, 0, 0);

    int sd0[8], sd1[8];
    float ps0 = 0.f, ps1 = 0.f, ps2 = 0.f, ps3 = 0.f;
#pragma unroll
    for (int s2 = 0; s2 < 8; s2++) {
      int ia = (int)(st0[2 * s2] * EXPA + EXPB);
      int ib = (int)(st0[2 * s2 + 1] * EXPA + EXPB);
      ps0 += __int_as_float(ia);
      ps1 += __int_as_float(ib);
      sd0[s2] = (int)__builtin_amdgcn_perm((unsigned)ib, (unsigned)ia, 0x07060302u);
    }
#pragma unroll
    for (int s2 = 0; s2 < 8; s2++) {
      int ia = (int)(st1[2 * s2] * EXPA + EXPB);
      int ib = (int)(st1[2 * s2 + 1] * EXPA + EXPB);
      ps2 += __int_as_float(ia);
      ps3 += __int_as_float(ib);
      sd1[s2] = (int)__builtin_amdgcn_perm((unsigned)ib, (unsigned)ia, 0x07060302u);
    }
    lrun += (ps0 + ps1) + (ps2 + ps3);
    __builtin_amdgcn_s_setprio(0);

    *(i32x4*)(pwr)        = (i32x4){sd0[0], sd0[1], sd0[2], sd0[3]};
    *(i32x4*)(pwr + 1024) = (i32x4){sd0[4], sd0[5], sd0[6], sd0[7]};
    *(i32x4*)(pwr + 2048) = (i32x4){sd1[0], sd1[1], sd1[2], sd1[3]};
    *(i32x4*)(pwr + 3072) = (i32x4){sd1[4], sd1[5], sd1[6], sd1[7]};
    __syncthreads();

    // ---- PV: V loaded once per (mt,m16), applied to both nt's P ----
    __builtin_amdgcn_s_setprio(1);
#pragma unroll
    for (int mt = 0; mt < 4; ++mt) {
      const short* pv = pvb + (size_t)(si * 4 + mt) * 16384;
      s16x8 vA0 = *(const s16x8*)(pv);
      s16x8 vA1 = *(const s16x8*)(pv + 4096);
      s16x8 vA2 = *(const s16x8*)(pv + 8192);
      s16x8 vA3 = *(const s16x8*)(pv + 12288);
      const char* p0 = lds + ((h * 2 + 0) * 4 + mt) * 4096 + prdO;
      const char* p1 = lds + ((h * 2 + 1) * 4 + mt) * 4096 + prdO;
      s16x8 pa0 = __builtin_bit_cast(s16x8, *(const i32x4*)(p0));
      s16x8 pb0 = __builtin_bit_cast(s16x8, *(const i32x4*)(p1));
      acc0 = __builtin_amdgcn_mfma_f32_32x32x16_bf16(vA0, pa0, acc0, 0, 0, 0);
      acc1 = __builtin_amdgcn_mfma_f32_32x32x16_bf16(vA0, pb0, acc1, 0, 0, 0);
      s16x8 pa1 = __builtin_bit_cast(s16x8, *(const i32x4*)(p0 + 1024));
      s16x8 pb1 = __builtin_bit_cast(s16x8, *(const i32x4*)(p1 + 1024));
      acc0 = __builtin_amdgcn_mfma_f32_32x32x16_bf16(vA1, pa1, acc0, 0, 0, 0);
      acc1 = __builtin_amdgcn_mfma_f32_32x32x16_bf16(vA1, pb1, acc1, 0, 0, 0);
      s16x8 pa2 = __builtin_bit_cast(s16x8, *(const i32x4*)(p0 + 2048));
      s16x8 pb2 = __builtin_bit_cast(s16x8, *(const i32x4*)(p1 + 2048));
      acc0 = __builtin_amdgcn_mfma_f32_32x32x16_bf16(vA2, pa2, acc0, 0, 0, 0);
      acc1 = __builtin_amdgcn_mfma_f32_32x32x16_bf16(vA2, pb2, acc1, 0, 0, 0);
      s16x8 pa3 = __builtin_bit_cast(s16x8, *(const i32x4*)(p0 + 3072));
      s16x8 pb3 = __builtin_bit_cast(s16x8, *(const i32x4*)(p1 + 3072));
      acc0 = __builtin_amdgcn_mfma_f32_32x32x16_bf16(vA3, pa3, acc0, 0, 0, 0);
      acc1 = __builtin_amdgcn_mfma_f32_32x32x16_bf16(vA3, pb3, acc1, 0, 0, 0);
    }
    __builtin_amdgcn_s_setprio(0);
    __syncthreads();
  }

  // hi-partner combine of own-tile column sums
  lrun += __shfl_xor(lrun, 32);

  // ---------------- epilogue ----------------
  float* mlb = (float*)lds;             // [16 waves][64 lanes] (P no longer needed)
  mlb[w * 64 + l] = lrun;
  __syncthreads();
  float L0 = 0.f, L1 = 0.f;
#pragma unroll
  for (int hh = 0; hh < 2; ++hh)
#pragma unroll
    for (int mt = 0; mt < 4; ++mt) {
      L0 += mlb[(hh * 8 + mt * 2 + 0) * 64 + l];
      L1 += mlb[(hh * 8 + mt * 2 + 1) * 64 + l];
    }
  __syncthreads();
  char* xch = lds;                      // [8 u][64 l][128B], swizzled
  const int xbase = (u * 64 + l) * 128;
  if (h == 1) {
#pragma unroll
    for (int i = 0; i < 8; i++) {
      f32x4 v;
#pragma unroll
      for (int r = 0; r < 4; r++) v[r] = (i >> 2) ? acc1[(i & 3) * 4 + r] : acc0[(i & 3) * 4 + r];
      *(f32x4*)(xch + xbase + ((i * 16) ^ ((l & 7) << 4))) = v;
    }
  }
  __syncthreads();
  if (h == 0) {
    const float inv0 = 0.1f / L0;
    const float inv1 = 0.1f / L1;
#pragma unroll
    for (int i = 0; i < 8; i++) {
      f32x4 po = *(const f32x4*)(xch + xbase + ((i * 16) ^ ((l & 7) << 4)));
      const int p_ = i & 3;
      const int ntw = i >> 2;
      const float inv = ntw ? inv1 : inv0;
      const int n = n0 + ntw * 32 + q;
      const int cbase = u * 32 + p_ * 8 + hi * 4;
#pragma unroll
      for (int r = 0; r < 4; r++) {
        const float own = ntw ? acc1[p_ * 4 + r] : acc0[p_ * 4 + r];
        const size_t idx = ((size_t)b * C_ + (cbase + r)) * N_ + n;
        out[idx] = x[idx] + (own + po[r]) * inv;
      }
    }
  }
}

extern "C" void kernel_launch(void* const* d_in, const int* in_sizes, int n_in,
                              void* d_out, int out_size, void* d_ws, size_t ws_size,
                              hipStream_t stream) {
  const float* x  = (const float*)d_in[0];
  const float* w1 = (const float*)d_in[1];
  const float* b1 = (const float*)d_in[2];
  float* out = (float*)d_out;
  short* fT  = (short*)d_ws;                         // [B][N][16] bf16, 512KB
  short* vtP = (short*)((char*)d_ws + 512 * 1024);   // [B][512][256][8] bf16, 8MB
  pre<<<dim3(768), dim3(256), 0, stream>>>(x, w1, b1, fT, vtP);
  flash13<<<dim3(256), dim3(1024), 0, stream>>>(x, vtP, fT, out);
}